// Round 4
// baseline (525.214 us; speedup 1.0000x reference)
//
#include <hip/hip_runtime.h>

typedef unsigned short u16;
typedef unsigned int u32;
typedef __attribute__((ext_vector_type(8))) short bf16x8;
typedef __attribute__((ext_vector_type(4))) float f32x4;
typedef __attribute__((ext_vector_type(4))) int i32x4;
typedef __attribute__((ext_vector_type(2))) unsigned int u32x2;

// T=4096 tokens, D=1024, F=4096, E=8, K=2. Inputs fp32.
// ws: xb(8M) | H(64M) | w1t(64M) | w3t(64M) | w2t(64M) | wa/alist/cnt

__device__ __forceinline__ u16 f2bf(float f) {
  u32 u = __builtin_bit_cast(u32, f);
  u += 0x7fffu + ((u >> 16) & 1u);
  return (u16)(u >> 16);
}
__device__ __forceinline__ u32 pack2(u16 a, u16 b) { return (u32)a | ((u32)b << 16); }

// XOR-swizzled LDS byte address for [row][64 bf16] tiles (128B rows); 16B-unit swizzle.
__device__ __forceinline__ char* lds_swz(void* base, int row, int byteInRow) {
  return (char*)base + (((row << 7) + byteInRow) ^ ((row & 7) << 4));
}

// async global->LDS, 16B per lane; LDS dest = wave-uniform base + lane*16, global src per-lane.
#define GLL16(g, l) __builtin_amdgcn_global_load_lds( \
    (const __attribute__((address_space(1))) void*)(g), \
    (__attribute__((address_space(3))) void*)(l), 16, 0, 0)

// ---------------- router ----------------
__global__ __launch_bounds__(256) void router_k(
    const float* __restrict__ x, const float* __restrict__ gw,
    float* __restrict__ probs, u16* __restrict__ xb,
    float* __restrict__ wa, int* __restrict__ alist, int* __restrict__ cnt)
{
  const int t = blockIdx.x;
  const int tid = threadIdx.x;
  f32x4 xv = ((const f32x4*)(x + (size_t)t * 1024))[tid];
  u32x2 hb;
  hb[0] = pack2(f2bf(xv[0]), f2bf(xv[1]));
  hb[1] = pack2(f2bf(xv[2]), f2bf(xv[3]));
  *(u32x2*)(xb + (size_t)t * 1024 + tid * 4) = hb;

  float acc[8];
#pragma unroll
  for (int e = 0; e < 8; ++e) acc[e] = 0.f;
  const float* g = gw + tid * 32;
#pragma unroll
  for (int j = 0; j < 4; ++j)
#pragma unroll
    for (int e = 0; e < 8; ++e) acc[e] = fmaf(xv[j], g[j * 8 + e], acc[e]);

#pragma unroll
  for (int e = 0; e < 8; ++e)
    for (int off = 32; off > 0; off >>= 1) acc[e] += __shfl_down(acc[e], off);

  __shared__ float red[4][8];
  const int lane = tid & 63, wid = tid >> 6;
  if (lane == 0) {
#pragma unroll
    for (int e = 0; e < 8; ++e) red[wid][e] = acc[e];
  }
  __syncthreads();
  if (tid == 0) {
    float p[8]; float mx = -1e30f;
#pragma unroll
    for (int e = 0; e < 8; ++e) { p[e] = red[0][e] + red[1][e] + red[2][e] + red[3][e]; mx = fmaxf(mx, p[e]); }
    float s = 0.f;
#pragma unroll
    for (int e = 0; e < 8; ++e) { p[e] = __expf(p[e] - mx); s += p[e]; }
    float inv = 1.f / s;
#pragma unroll
    for (int e = 0; e < 8; ++e) { p[e] *= inv; probs[(size_t)t * 8 + e] = p[e]; }
    int i0 = 0;
#pragma unroll
    for (int e = 1; e < 8; ++e) if (p[e] > p[i0]) i0 = e;
    int i1 = (i0 == 0) ? 1 : 0;
#pragma unroll
    for (int e = 0; e < 8; ++e) if (e != i0 && p[e] > p[i1]) i1 = e;
    float s2 = p[i0] + p[i1];
    int pos0 = atomicAdd(&cnt[i0], 1); alist[i0 * 4096 + pos0] = t * 2;
    int pos1 = atomicAdd(&cnt[i1], 1); alist[i1 * 4096 + pos1] = t * 2 + 1;
    wa[t * 2]     = p[i0] / s2;
    wa[t * 2 + 1] = p[i1] / s2;
  }
}

// ---------------- weight prep (merged): [R][C] fp32 -> [C][R] bf16, all three tensors ----------------
__global__ __launch_bounds__(256) void wprep_k(
    const float* __restrict__ w1, const float* __restrict__ w3, const float* __restrict__ w2,
    u16* __restrict__ w1t, u16* __restrict__ w3t, u16* __restrict__ w2t)
{
  const int bid = blockIdx.x;            // 0..24575
  const float* src; u16* dst; int R, C, x, y, e;
  if (bid < 16384) {
    int sel = bid >> 13;
    int t0 = bid & 8191;
    e = t0 >> 10;
    int rem = t0 & 1023;
    x = rem & 63; y = rem >> 6;
    R = 1024; C = 4096;
    src = (sel ? w3 : w1); dst = (sel ? w3t : w1t);
  } else {
    int t0 = bid - 16384;
    e = t0 >> 10;
    int rem = t0 & 1023;
    x = rem & 15; y = rem >> 4;
    R = 4096; C = 1024;
    src = w2; dst = w2t;
  }
  src += (size_t)e * 4194304;
  dst += (size_t)e * 4194304;
  const int c0 = x * 64, r0 = y * 64;
  __shared__ u16 t[64][72];
  const int tid = threadIdx.x;
  const int rr = (tid >> 4) * 4, cc = (tid & 15) * 4;
  f32x4 v[4];
#pragma unroll
  for (int j = 0; j < 4; ++j) v[j] = *(const f32x4*)(src + (size_t)(r0 + rr + j) * C + c0 + cc);
#pragma unroll
  for (int c = 0; c < 4; ++c) {
    u32x2 p;
    p[0] = pack2(f2bf(v[0][c]), f2bf(v[1][c]));
    p[1] = pack2(f2bf(v[2][c]), f2bf(v[3][c]));
    *(u32x2*)&t[cc + c][rr] = p;
  }
  __syncthreads();
  const int c = tid >> 2, rs = (tid & 3) * 16;
  i32x4 a0 = *(const i32x4*)&t[c][rs];
  i32x4 a1 = *(const i32x4*)&t[c][rs + 8];
  u16* dp = dst + (size_t)(c0 + c) * R + r0 + rs;
  *(i32x4*)dp = a0;
  *(i32x4*)(dp + 8) = a1;
}

// ---------------- gemm1: H = silu(x@w1) * (x@w3) ----------------
// tile 128M x (64+64)N, BK=64, 4 waves. Counted-vmcnt pipeline:
// B double-buffered via global_load_lds; A prefetched via regs, ds_write after compute barrier.
__global__ __launch_bounds__(256, 3) void gemm1_k(
    const u16* __restrict__ xb, const u16* __restrict__ w1t, const u16* __restrict__ w3t,
    const int* __restrict__ alist, const int* __restrict__ cnt, u16* __restrict__ H)
{
  const int e = blockIdx.z;
  const int mc = cnt[e];
  const int m0 = blockIdx.y * 128;
  if (m0 >= mc) return;
  const int n0 = blockIdx.x * 64;
  const int tid = threadIdx.x;

  __shared__ u16 As[128 * 64];
  __shared__ u16 Bs[2][2][64 * 64];    // [buf][mat]
  __shared__ int rowid[128];

  if (tid < 128) rowid[tid] = (m0 + tid < mc) ? alist[e * 4096 + m0 + tid] : -1;
  __syncthreads();

  const int l = tid & 63, w = tid >> 6;

  // A-prefetch (regs): thread t -> row t>>1, 32-elem half (t&1). Unconditional clamped load.
  const int arow = tid >> 1, ah = tid & 1;
  const int id_a = rowid[arow];
  const u16* asrc = xb + (size_t)(id_a < 0 ? 0 : (id_a >> 1)) * 1024 + ah * 32;
  char* awr[4];
#pragma unroll
  for (int j = 0; j < 4; ++j) awr[j] = lds_swz(As, arow, ah * 64 + j * 16);

  // B staging via GLL16: wave w -> mat (w>>1), rows (w&1)*32 + q*8 .. +7
  const u16* wt = (w >> 1) ? w3t : w1t;
  const u16* bps[4]; u16* bl0[4];
#pragma unroll
  for (int q = 0; q < 4; ++q) {
    int rb = 32 * (w & 1) + 8 * q + (l >> 3);
    bps[q] = wt + (size_t)e * 4194304 + (size_t)(n0 + rb) * 1024 + ((l & 7) ^ (rb & 7)) * 8;
    bl0[q] = &Bs[0][w >> 1][(32 * (w & 1) + 8 * q) * 64];
  }

  const int wm = (w >> 1) * 64, wn = (w & 1) * 32;
  const int l15 = l & 15, lg = l >> 4;

  f32x4 acc1[4][2], acc3[4][2];
  const f32x4 zf = {0.f, 0.f, 0.f, 0.f};
#pragma unroll
  for (int mi = 0; mi < 4; ++mi) { acc1[mi][0] = zf; acc1[mi][1] = zf; acc3[mi][0] = zf; acc3[mi][1] = zf; }

  i32x4 a2[4];
  // ---- prologue: tile 0
#pragma unroll
  for (int j = 0; j < 4; ++j) a2[j] = *(const i32x4*)(asrc + j * 8);          // 4 vm
#pragma unroll
  for (int q = 0; q < 4; ++q) GLL16(bps[q], bl0[q]);                           // 4 vm
  asm volatile("s_waitcnt vmcnt(4)" ::: "memory");                             // A(0) done
#pragma unroll
  for (int j = 0; j < 4; ++j) *(i32x4*)awr[j] = a2[j];

#define G1_COMPUTE(BO)                                                          \
  _Pragma("unroll")                                                             \
  for (int ks = 0; ks < 2; ++ks) {                                              \
    const int kb = ks * 64 + lg * 16;                                           \
    bf16x8 af[4];                                                               \
    _Pragma("unroll")                                                           \
    for (int mi = 0; mi < 4; ++mi)                                              \
      af[mi] = *(const bf16x8*)lds_swz(As, wm + mi * 16 + l15, kb);             \
    _Pragma("unroll")                                                           \
    for (int ni = 0; ni < 2; ++ni) {                                            \
      bf16x8 b1 = *(const bf16x8*)lds_swz(&Bs[0][0][0] + (BO), wn + ni * 16 + l15, kb);        \
      bf16x8 b3 = *(const bf16x8*)lds_swz(&Bs[0][0][0] + (BO) + 4096, wn + ni * 16 + l15, kb); \
      _Pragma("unroll")                                                         \
      for (int mi = 0; mi < 4; ++mi) {                                          \
        acc1[mi][ni] = __builtin_amdgcn_mfma_f32_16x16x32_bf16(af[mi], b1, acc1[mi][ni], 0, 0, 0); \
        acc3[mi][ni] = __builtin_amdgcn_mfma_f32_16x16x32_bf16(af[mi], b3, acc3[mi][ni], 0, 0, 0); \
      }                                                                         \
    }                                                                           \
  }

#pragma unroll 2
  for (int kt = 0; kt < 15; ++kt) {
    const int ko = (kt + 1) * 64;
#pragma unroll
    for (int j = 0; j < 4; ++j) a2[j] = *(const i32x4*)(asrc + ko + j * 8);    // 4 vm (oldest of this iter)
#pragma unroll
    for (int q = 0; q < 4; ++q) GLL16(bps[q] + ko, bl0[q] + ((kt + 1) & 1) * 8192);  // 4 vm
    asm volatile("s_waitcnt vmcnt(8) lgkmcnt(0)" ::: "memory");                // B(kt) landed, A ds_writes done
    __builtin_amdgcn_s_barrier();
    G1_COMPUTE((kt & 1) * 8192);
    __builtin_amdgcn_s_barrier();
    asm volatile("s_waitcnt vmcnt(4)" ::: "memory");                           // A(kt+1) regs ready
#pragma unroll
    for (int j = 0; j < 4; ++j) *(i32x4*)awr[j] = a2[j];
  }
  // ---- epilogue tile 15
  asm volatile("s_waitcnt vmcnt(0) lgkmcnt(0)" ::: "memory");
  __builtin_amdgcn_s_barrier();
  G1_COMPUTE(8192);

#pragma unroll
  for (int mi = 0; mi < 4; ++mi) {
    const int rb = wm + mi * 16 + lg * 4;
#pragma unroll
    for (int ni = 0; ni < 2; ++ni) {
      const int col = n0 + wn + ni * 16 + l15;
      f32x4 c1 = acc1[mi][ni], c3 = acc3[mi][ni];
#pragma unroll
      for (int j = 0; j < 4; ++j) {
        int id = rowid[rb + j];
        if (id >= 0) {
          float a = c1[j];
          float h = (a / (1.f + __expf(-a))) * c3[j];
          H[(size_t)id * 4096 + col] = f2bf(h);
        }
      }
    }
  }
}

// ---------------- gemm2: out[token] += wa * (H @ w2), split-K=2, fused combine ----------------
// tile 128M x 128N, BK=64, 4 waves; same counted-vmcnt pipeline.
__global__ __launch_bounds__(256, 3) void gemm2_k(
    const u16* __restrict__ H, const u16* __restrict__ w2t,
    const int* __restrict__ alist, const int* __restrict__ cnt,
    const float* __restrict__ wa, float* __restrict__ out)
{
  const int e = blockIdx.z;
  const int mc = cnt[e];
  const int yy = blockIdx.y;
  const int kh = yy & 1;
  const int m0 = (yy >> 1) * 128;
  if (m0 >= mc) return;
  const int n0 = blockIdx.x * 128;
  const int tid = threadIdx.x;

  __shared__ u16 As[128 * 64];
  __shared__ u16 Bs[2][128 * 64];
  __shared__ int rowid[128];
  __shared__ float rw[128];

  if (tid < 128) {
    int id = (m0 + tid < mc) ? alist[e * 4096 + m0 + tid] : -1;
    rowid[tid] = id;
    rw[tid] = (id >= 0) ? wa[id] : 0.f;
  }
  __syncthreads();

  const int l = tid & 63, w = tid >> 6;
  const size_t kbase = (size_t)kh * 2048;

  const int arow = tid >> 1, ah = tid & 1;
  const int id_a = rowid[arow];
  const u16* asrc = H + (size_t)(id_a < 0 ? 0 : id_a) * 4096 + kbase + ah * 32;
  char* awr[4];
#pragma unroll
  for (int j = 0; j < 4; ++j) awr[j] = lds_swz(As, arow, ah * 64 + j * 16);

  const u16* bps[4]; u16* bl0[4];
#pragma unroll
  for (int q = 0; q < 4; ++q) {
    int rb = 32 * w + 8 * q + (l >> 3);
    bps[q] = w2t + (size_t)e * 4194304 + (size_t)(n0 + rb) * 4096 + kbase + ((l & 7) ^ (rb & 7)) * 8;
    bl0[q] = &Bs[0][(32 * w + 8 * q) * 64];
  }

  const int wm = (w >> 1) * 64, wn = (w & 1) * 64;
  const int l15 = l & 15, lg = l >> 4;

  f32x4 acc[4][4];
  const f32x4 zf = {0.f, 0.f, 0.f, 0.f};
#pragma unroll
  for (int mi = 0; mi < 4; ++mi)
#pragma unroll
    for (int ni = 0; ni < 4; ++ni) acc[mi][ni] = zf;

  i32x4 a2[4];
#pragma unroll
  for (int j = 0; j < 4; ++j) a2[j] = *(const i32x4*)(asrc + j * 8);
#pragma unroll
  for (int q = 0; q < 4; ++q) GLL16(bps[q], bl0[q]);
  asm volatile("s_waitcnt vmcnt(4)" ::: "memory");
#pragma unroll
  for (int j = 0; j < 4; ++j) *(i32x4*)awr[j] = a2[j];

#define G2_COMPUTE(BO)                                                          \
  _Pragma("unroll")                                                             \
  for (int ks = 0; ks < 2; ++ks) {                                              \
    const int kb = ks * 64 + lg * 16;                                           \
    bf16x8 af[4];                                                               \
    _Pragma("unroll")                                                           \
    for (int mi = 0; mi < 4; ++mi)                                              \
      af[mi] = *(const bf16x8*)lds_swz(As, wm + mi * 16 + l15, kb);             \
    _Pragma("unroll")                                                           \
    for (int ni = 0; ni < 4; ++ni) {                                            \
      bf16x8 bfb = *(const bf16x8*)lds_swz(&Bs[0][0] + (BO), wn + ni * 16 + l15, kb); \
      _Pragma("unroll")                                                         \
      for (int mi = 0; mi < 4; ++mi)                                            \
        acc[mi][ni] = __builtin_amdgcn_mfma_f32_16x16x32_bf16(af[mi], bfb, acc[mi][ni], 0, 0, 0); \
    }                                                                           \
  }

#pragma unroll 2
  for (int kt = 0; kt < 31; ++kt) {
    const int ko = (kt + 1) * 64;
#pragma unroll
    for (int j = 0; j < 4; ++j) a2[j] = *(const i32x4*)(asrc + ko + j * 8);
#pragma unroll
    for (int q = 0; q < 4; ++q) GLL16(bps[q] + ko, bl0[q] + ((kt + 1) & 1) * 8192);
    asm volatile("s_waitcnt vmcnt(8) lgkmcnt(0)" ::: "memory");
    __builtin_amdgcn_s_barrier();
    G2_COMPUTE((kt & 1) * 8192);
    __builtin_amdgcn_s_barrier();
    asm volatile("s_waitcnt vmcnt(4)" ::: "memory");
#pragma unroll
    for (int j = 0; j < 4; ++j) *(i32x4*)awr[j] = a2[j];
  }
  asm volatile("s_waitcnt vmcnt(0) lgkmcnt(0)" ::: "memory");
  __builtin_amdgcn_s_barrier();
  G2_COMPUTE(8192);

#pragma unroll
  for (int mi = 0; mi < 4; ++mi) {
    const int rb = wm + mi * 16 + lg * 4;
#pragma unroll
    for (int ni = 0; ni < 4; ++ni) {
      const int col = n0 + wn + ni * 16 + l15;
      f32x4 c = acc[mi][ni];
#pragma unroll
      for (int j = 0; j < 4; ++j) {
        int rr = rb + j;
        int id = rowid[rr];
        if (id >= 0)
          unsafeAtomicAdd(&out[(size_t)(id >> 1) * 1024 + col], c[j] * rw[rr]);
      }
    }
  }
}

extern "C" void kernel_launch(void* const* d_in, const int* in_sizes, int n_in,
                              void* d_out, int out_size, void* d_ws, size_t ws_size,
                              hipStream_t stream)
{
  (void)in_sizes; (void)n_in; (void)out_size; (void)ws_size;
  const float* x  = (const float*)d_in[0];
  const float* gw = (const float*)d_in[1];
  const float* w1 = (const float*)d_in[2];
  const float* w3 = (const float*)d_in[3];
  const float* w2 = (const float*)d_in[4];
  float* out   = (float*)d_out;
  float* probs = out + (size_t)4096 * 1024;

  const size_t MB = (size_t)1 << 20;
  char* ws = (char*)d_ws;
  u16*   xb    = (u16*)(ws);
  u16*   H     = (u16*)(ws + 8 * MB);
  u16*   w1t   = (u16*)(ws + 72 * MB);
  u16*   w3t   = (u16*)(ws + 136 * MB);
  u16*   w2t   = (u16*)(ws + 200 * MB);
  float* wa    = (float*)(ws + 264 * MB);
  int*   alist = (int*)(ws + 264 * MB + 32768);
  int*   cnt   = (int*)(ws + 264 * MB + 32768 + 131072);

  hipMemsetAsync(cnt, 0, 8 * sizeof(int), stream);
  hipMemsetAsync(out, 0, (size_t)4096 * 1024 * sizeof(float), stream);
  router_k<<<4096, 256, 0, stream>>>(x, gw, probs, xb, wa, alist, cnt);
  wprep_k<<<24576, 256, 0, stream>>>(w1, w3, w2, w1t, w3t, w2t);
  gemm1_k<<<dim3(64, 32, 8), 256, 0, stream>>>(xb, w1t, w3t, alist, cnt, H);
  gemm2_k<<<dim3(8, 64, 8), 256, 0, stream>>>(H, w2t, alist, cnt, wa, out);
}

// Round 5
// 485.460 us; speedup vs baseline: 1.0819x; 1.0819x over previous
//
#include <hip/hip_runtime.h>

typedef unsigned short u16;
typedef unsigned int u32;
typedef __attribute__((ext_vector_type(8))) short bf16x8;
typedef __attribute__((ext_vector_type(4))) float f32x4;
typedef __attribute__((ext_vector_type(4))) int i32x4;
typedef __attribute__((ext_vector_type(2))) unsigned int u32x2;

// T=4096 tokens, D=1024, F=4096, E=8, K=2. Inputs fp32.
// ws: xb(8M) | H(64M) | w1t(64M) | w3t(64M) | w2t(64M) | wa/alist/cnt

__device__ __forceinline__ u16 f2bf(float f) {
  u32 u = __builtin_bit_cast(u32, f);
  u += 0x7fffu + ((u >> 16) & 1u);
  return (u16)(u >> 16);
}
__device__ __forceinline__ u32 pack2(u16 a, u16 b) { return (u32)a | ((u32)b << 16); }

// XOR-swizzled LDS byte address for [row][64 bf16] tiles (128B rows); 16B-unit swizzle.
__device__ __forceinline__ char* lds_swz(void* base, int row, int byteInRow) {
  return (char*)base + (((row << 7) + byteInRow) ^ ((row & 7) << 4));
}

// async global->LDS, 16B per lane; LDS dest = wave-uniform base + lane*16, global src per-lane.
#define GLL16(g, l) __builtin_amdgcn_global_load_lds( \
    (const __attribute__((address_space(1))) void*)(g), \
    (__attribute__((address_space(3))) void*)(l), 16, 0, 0)

// ---- 64x64 fp32->bf16 transpose tile helper (uses caller's LDS) ----
__device__ __forceinline__ void wtrans_tile(const float* __restrict__ src, u16* __restrict__ dst,
                                            int R, int C, int c0, int r0, void* lds)
{
  u16 (*t)[72] = (u16 (*)[72])lds;
  const int tid = threadIdx.x;
  const int rr = (tid >> 4) * 4, cc = (tid & 15) * 4;
  f32x4 v[4];
#pragma unroll
  for (int j = 0; j < 4; ++j) v[j] = *(const f32x4*)(src + (size_t)(r0 + rr + j) * C + c0 + cc);
#pragma unroll
  for (int c = 0; c < 4; ++c) {
    u32x2 p;
    p[0] = pack2(f2bf(v[0][c]), f2bf(v[1][c]));
    p[1] = pack2(f2bf(v[2][c]), f2bf(v[3][c]));
    *(u32x2*)&t[cc + c][rr] = p;
  }
  __syncthreads();
  const int c = tid >> 2, rs = (tid & 3) * 16;
  i32x4 a0 = *(const i32x4*)&t[c][rs];
  i32x4 a1 = *(const i32x4*)&t[c][rs + 8];
  u16* dp = dst + (size_t)(c0 + c) * R + r0 + rs;
  *(i32x4*)dp = a0;
  *(i32x4*)(dp + 8) = a1;
}

// ---------------- launch A: w1/w3 transpose + router, one dispatch ----------------
__global__ __launch_bounds__(256) void prep13_router_k(
    const float* __restrict__ w1, const float* __restrict__ w3,
    u16* __restrict__ w1t, u16* __restrict__ w3t,
    const float* __restrict__ x, const float* __restrict__ gw,
    float* __restrict__ probs, u16* __restrict__ xb,
    float* __restrict__ wa, int* __restrict__ alist, int* __restrict__ cnt)
{
  __shared__ __align__(16) char smem[9216];
  const int bid = blockIdx.x;
  if (bid < 16384) {
    const int sel = bid >> 13;
    const int t0 = bid & 8191;
    const int e = t0 >> 10;
    const int rem = t0 & 1023;
    const int xt = rem & 63, yt = rem >> 6;
    const float* src = (sel ? w3 : w1) + (size_t)e * 4194304;
    u16* dst = (sel ? w3t : w1t) + (size_t)e * 4194304;
    wtrans_tile(src, dst, 1024, 4096, xt * 64, yt * 64, smem);
    return;
  }
  // ---- router block
  const int t = bid - 16384;
  const int tid = threadIdx.x;
  f32x4 xv = ((const f32x4*)(x + (size_t)t * 1024))[tid];
  u32x2 hb;
  hb[0] = pack2(f2bf(xv[0]), f2bf(xv[1]));
  hb[1] = pack2(f2bf(xv[2]), f2bf(xv[3]));
  *(u32x2*)(xb + (size_t)t * 1024 + tid * 4) = hb;

  float acc[8];
#pragma unroll
  for (int e = 0; e < 8; ++e) acc[e] = 0.f;
  const float* g = gw + tid * 32;
#pragma unroll
  for (int j = 0; j < 4; ++j)
#pragma unroll
    for (int e = 0; e < 8; ++e) acc[e] = fmaf(xv[j], g[j * 8 + e], acc[e]);

#pragma unroll
  for (int e = 0; e < 8; ++e)
    for (int off = 32; off > 0; off >>= 1) acc[e] += __shfl_down(acc[e], off);

  float* red = (float*)smem;             // [4][8]
  const int lane = tid & 63, wid = tid >> 6;
  if (lane == 0) {
#pragma unroll
    for (int e = 0; e < 8; ++e) red[wid * 8 + e] = acc[e];
  }
  __syncthreads();
  if (tid == 0) {
    float p[8]; float mx = -1e30f;
#pragma unroll
    for (int e = 0; e < 8; ++e) { p[e] = red[e] + red[8 + e] + red[16 + e] + red[24 + e]; mx = fmaxf(mx, p[e]); }
    float s = 0.f;
#pragma unroll
    for (int e = 0; e < 8; ++e) { p[e] = __expf(p[e] - mx); s += p[e]; }
    float inv = 1.f / s;
#pragma unroll
    for (int e = 0; e < 8; ++e) { p[e] *= inv; probs[(size_t)t * 8 + e] = p[e]; }
    int i0 = 0;
#pragma unroll
    for (int e = 1; e < 8; ++e) if (p[e] > p[i0]) i0 = e;
    int i1 = (i0 == 0) ? 1 : 0;
#pragma unroll
    for (int e = 0; e < 8; ++e) if (e != i0 && p[e] > p[i1]) i1 = e;
    float s2 = p[i0] + p[i1];
    int pos0 = atomicAdd(&cnt[i0], 1); alist[i0 * 4096 + pos0] = t * 2;
    int pos1 = atomicAdd(&cnt[i1], 1); alist[i1 * 4096 + pos1] = t * 2 + 1;
    wa[t * 2]     = p[i0] / s2;
    wa[t * 2 + 1] = p[i1] / s2;
  }
}

// ---------------- launch B: gemm1 (R3-proven) + w2 transpose overlaid ----------------
// blockIdx.x < 64: gemm1 N-tile; >= 64: w2-prep (4 tiles each).
__global__ __launch_bounds__(256, 2) void gemm1w2_k(
    const u16* __restrict__ xb, const u16* __restrict__ w1t, const u16* __restrict__ w3t,
    const int* __restrict__ alist, const int* __restrict__ cnt, u16* __restrict__ H,
    const float* __restrict__ w2, u16* __restrict__ w2t)
{
  __shared__ __align__(16) char smem[33280];
  const int e = blockIdx.z;
  const int bx = blockIdx.x;

  if (bx >= 64) {
    // ---- w2 prep: [4096][1024] fp32 -> [1024][4096] bf16 for expert e
    const float* src = w2 + (size_t)e * 4194304;
    u16* dst = w2t + (size_t)e * 4194304;
    const int slot = (bx - 64) * 32 + blockIdx.y;   // 0..255
#pragma unroll
    for (int j = 0; j < 4; ++j) {
      const int tj = slot * 4 + j;                  // 0..1023
      const int cx = tj & 15, ry = tj >> 4;         // C=1024 -> 16 c-tiles, R=4096 -> 64 r-tiles
      wtrans_tile(src, dst, 4096, 1024, cx * 64, ry * 64, smem);
      __syncthreads();
    }
    return;
  }

  u16* As = (u16*)smem;                  // [128*64]
  u16* Bs = (u16*)(smem + 16384);        // [2][64*64]
  int* rowid = (int*)(smem + 32768);     // [128]

  const int mc = cnt[e];
  const int m0 = blockIdx.y * 128;
  if (m0 >= mc) return;
  const int n0 = bx * 64;
  const int tid = threadIdx.x;

  if (tid < 128) rowid[tid] = (m0 + tid < mc) ? alist[e * 4096 + m0 + tid] : -1;
  __syncthreads();

  const int l = tid & 63, w = tid >> 6;
  const u16* wt = (w >> 1) ? w3t : w1t;
  u16* bbase = Bs + (w >> 1) * 4096;

  const u16* aps[4]; const u16* bps[4];
  u16* ald[4]; u16* bld[4];
#pragma unroll
  for (int q = 0; q < 4; ++q) {
    int ra = 32 * w + 8 * q + (l >> 3);
    int id = rowid[ra];
    aps[q] = xb + (size_t)(id < 0 ? 0 : (id >> 1)) * 1024 + ((l & 7) ^ (ra & 7)) * 8;
    ald[q] = As + (32 * w + 8 * q) * 64;
    int rb = 32 * (w & 1) + 8 * q + (l >> 3);
    bps[q] = wt + (size_t)e * 4194304 + (size_t)(n0 + rb) * 1024 + ((l & 7) ^ (rb & 7)) * 8;
    bld[q] = bbase + (32 * (w & 1) + 8 * q) * 64;
  }

  const int wm = (w >> 1) * 64, wn = (w & 1) * 32;
  const int l15 = l & 15, lg = l >> 4;

  f32x4 acc1[4][2], acc3[4][2];
  const f32x4 zf = {0.f, 0.f, 0.f, 0.f};
#pragma unroll
  for (int mi = 0; mi < 4; ++mi) { acc1[mi][0] = zf; acc1[mi][1] = zf; acc3[mi][0] = zf; acc3[mi][1] = zf; }

  for (int kt = 0; kt < 16; ++kt) {
    const int ko = kt * 64;
#pragma unroll
    for (int q = 0; q < 4; ++q) GLL16(aps[q] + ko, ald[q]);
#pragma unroll
    for (int q = 0; q < 4; ++q) GLL16(bps[q] + ko, bld[q]);
    __syncthreads();
#pragma unroll
    for (int ks = 0; ks < 2; ++ks) {
      const int kb = ks * 64 + lg * 16;
      bf16x8 af[4];
#pragma unroll
      for (int mi = 0; mi < 4; ++mi)
        af[mi] = *(const bf16x8*)lds_swz(As, wm + mi * 16 + l15, kb);
#pragma unroll
      for (int ni = 0; ni < 2; ++ni) {
        bf16x8 b1 = *(const bf16x8*)lds_swz(Bs, wn + ni * 16 + l15, kb);
        bf16x8 b3 = *(const bf16x8*)lds_swz(Bs + 4096, wn + ni * 16 + l15, kb);
#pragma unroll
        for (int mi = 0; mi < 4; ++mi) {
          acc1[mi][ni] = __builtin_amdgcn_mfma_f32_16x16x32_bf16(af[mi], b1, acc1[mi][ni], 0, 0, 0);
          acc3[mi][ni] = __builtin_amdgcn_mfma_f32_16x16x32_bf16(af[mi], b3, acc3[mi][ni], 0, 0, 0);
        }
      }
    }
    __syncthreads();
  }

#pragma unroll
  for (int mi = 0; mi < 4; ++mi) {
    const int rb = wm + mi * 16 + lg * 4;
#pragma unroll
    for (int ni = 0; ni < 2; ++ni) {
      const int col = n0 + wn + ni * 16 + l15;
      f32x4 c1 = acc1[mi][ni], c3 = acc3[mi][ni];
#pragma unroll
      for (int j = 0; j < 4; ++j) {
        int id = rowid[rb + j];
        if (id >= 0) {
          float a = c1[j];
          float h = (a / (1.f + __expf(-a))) * c3[j];
          H[(size_t)id * 4096 + col] = f2bf(h);
        }
      }
    }
  }
}

// ---------------- gemm2: out[token] += wa * (H @ w2), split-K=2, fused combine (R3-proven) ----------------
__global__ __launch_bounds__(256, 2) void gemm2_k(
    const u16* __restrict__ H, const u16* __restrict__ w2t,
    const int* __restrict__ alist, const int* __restrict__ cnt,
    const float* __restrict__ wa, float* __restrict__ out)
{
  const int e = blockIdx.z;
  const int mc = cnt[e];
  const int yy = blockIdx.y;
  const int kh = yy & 1;
  const int m0 = (yy >> 1) * 128;
  if (m0 >= mc) return;
  const int n0 = blockIdx.x * 128;
  const int tid = threadIdx.x;

  __shared__ u16 As[128 * 64];
  __shared__ u16 Bs[128 * 64];
  __shared__ int rowid[128];
  __shared__ float rw[128];

  if (tid < 128) {
    int id = (m0 + tid < mc) ? alist[e * 4096 + m0 + tid] : -1;
    rowid[tid] = id;
    rw[tid] = (id >= 0) ? wa[id] : 0.f;
  }
  __syncthreads();

  const int l = tid & 63, w = tid >> 6;
  const size_t kbase = (size_t)kh * 2048;
  const u16* aps[4]; const u16* bps[4];
  u16* ald[4]; u16* bld[4];
#pragma unroll
  for (int q = 0; q < 4; ++q) {
    int ra = 32 * w + 8 * q + (l >> 3);
    int id = rowid[ra];
    aps[q] = H + (size_t)(id < 0 ? 0 : id) * 4096 + kbase + ((l & 7) ^ (ra & 7)) * 8;
    ald[q] = As + (32 * w + 8 * q) * 64;
    int rb = 32 * w + 8 * q + (l >> 3);
    bps[q] = w2t + (size_t)e * 4194304 + (size_t)(n0 + rb) * 4096 + kbase + ((l & 7) ^ (rb & 7)) * 8;
    bld[q] = Bs + (32 * w + 8 * q) * 64;
  }

  const int wm = (w >> 1) * 64, wn = (w & 1) * 64;
  const int l15 = l & 15, lg = l >> 4;

  f32x4 acc[4][4];
  const f32x4 zf = {0.f, 0.f, 0.f, 0.f};
#pragma unroll
  for (int mi = 0; mi < 4; ++mi)
#pragma unroll
    for (int ni = 0; ni < 4; ++ni) acc[mi][ni] = zf;

  for (int kt = 0; kt < 32; ++kt) {
    const int ko = kt * 64;
#pragma unroll
    for (int q = 0; q < 4; ++q) GLL16(aps[q] + ko, ald[q]);
#pragma unroll
    for (int q = 0; q < 4; ++q) GLL16(bps[q] + ko, bld[q]);
    __syncthreads();
#pragma unroll
    for (int ks = 0; ks < 2; ++ks) {
      const int kb = ks * 64 + lg * 16;
      bf16x8 af[4];
#pragma unroll
      for (int mi = 0; mi < 4; ++mi)
        af[mi] = *(const bf16x8*)lds_swz(As, wm + mi * 16 + l15, kb);
#pragma unroll
      for (int ni = 0; ni < 4; ++ni) {
        bf16x8 bfb = *(const bf16x8*)lds_swz(Bs, wn + ni * 16 + l15, kb);
#pragma unroll
        for (int mi = 0; mi < 4; ++mi)
          acc[mi][ni] = __builtin_amdgcn_mfma_f32_16x16x32_bf16(af[mi], bfb, acc[mi][ni], 0, 0, 0);
      }
    }
    __syncthreads();
  }

#pragma unroll
  for (int mi = 0; mi < 4; ++mi) {
    const int rb = wm + mi * 16 + lg * 4;
#pragma unroll
    for (int ni = 0; ni < 4; ++ni) {
      const int col = n0 + wn + ni * 16 + l15;
      f32x4 c = acc[mi][ni];
#pragma unroll
      for (int j = 0; j < 4; ++j) {
        int rr = rb + j;
        int id = rowid[rr];
        if (id >= 0)
          unsafeAtomicAdd(&out[(size_t)(id >> 1) * 1024 + col], c[j] * rw[rr]);
      }
    }
  }
}

extern "C" void kernel_launch(void* const* d_in, const int* in_sizes, int n_in,
                              void* d_out, int out_size, void* d_ws, size_t ws_size,
                              hipStream_t stream)
{
  (void)in_sizes; (void)n_in; (void)out_size; (void)ws_size;
  const float* x  = (const float*)d_in[0];
  const float* gw = (const float*)d_in[1];
  const float* w1 = (const float*)d_in[2];
  const float* w3 = (const float*)d_in[3];
  const float* w2 = (const float*)d_in[4];
  float* out   = (float*)d_out;
  float* probs = out + (size_t)4096 * 1024;

  const size_t MB = (size_t)1 << 20;
  char* ws = (char*)d_ws;
  u16*   xb    = (u16*)(ws);
  u16*   H     = (u16*)(ws + 8 * MB);
  u16*   w1t   = (u16*)(ws + 72 * MB);
  u16*   w3t   = (u16*)(ws + 136 * MB);
  u16*   w2t   = (u16*)(ws + 200 * MB);
  float* wa    = (float*)(ws + 264 * MB);
  int*   alist = (int*)(ws + 264 * MB + 32768);
  int*   cnt   = (int*)(ws + 264 * MB + 32768 + 131072);

  hipMemsetAsync(cnt, 0, 8 * sizeof(int), stream);
  hipMemsetAsync(out, 0, (size_t)4096 * 1024 * sizeof(float), stream);
  prep13_router_k<<<20480, 256, 0, stream>>>(w1, w3, w1t, w3t, x, gw, probs, xb, wa, alist, cnt);
  gemm1w2_k<<<dim3(72, 32, 8), 256, 0, stream>>>(xb, w1t, w3t, alist, cnt, H, w2, w2t);
  gemm2_k<<<dim3(8, 64, 8), 256, 0, stream>>>(H, w2t, alist, cnt, wa, out);
}